// Round 9
// baseline (291.373 us; speedup 1.0000x reference)
//
#include <hip/hip_runtime.h>

typedef __attribute__((ext_vector_type(8))) short bf16x8;
typedef __attribute__((ext_vector_type(4))) float f32x4;

#define LOG2E 1.44269504088896340736f

// Average-trace constant from the Python module (length 120).
__device__ __constant__ float AVG_D[120] = {
    0.0256f,0.0823f,0.1157f,0.1315f,0.1366f,0.1369f,0.1347f,0.1308f,0.1259f,0.1205f,
    0.1146f,0.1086f,0.1028f,0.0970f,0.0913f,0.0858f,0.0805f,0.0756f,0.0708f,0.0664f,
    0.0623f,0.0584f,0.0549f,0.0515f,0.0485f,0.0456f,0.0429f,0.0404f,0.0381f,0.0360f,
    0.0340f,0.0321f,0.0304f,0.0287f,0.0272f,0.0258f,0.0245f,0.0233f,0.0222f,0.0211f,
    0.0201f,0.0191f,0.0182f,0.0173f,0.0165f,0.0158f,0.0150f,0.0143f,0.0137f,0.0130f,
    0.0125f,0.0119f,0.0114f,0.0108f,0.0104f,0.0099f,0.0095f,0.0091f,0.0087f,0.0083f,
    0.0080f,0.0077f,0.0074f,0.0071f,0.0068f,0.0065f,0.0062f,0.0060f,0.0058f,0.0055f,
    0.0053f,0.0050f,0.0049f,0.0047f,0.0045f,0.0044f,0.0042f,0.0040f,0.0039f,0.0038f,
    0.0036f,0.0034f,0.0033f,0.0032f,0.0031f,0.0030f,0.0029f,0.0028f,0.0027f,0.0026f,
    0.0025f,0.0024f,0.0023f,0.0022f,0.0021f,0.0021f,0.0020f,0.0019f,0.0018f,0.0018f,
    0.0017f,0.0017f,0.0016f,0.0016f,0.0015f,0.0015f,0.0014f,0.0014f,0.0013f,0.0013f,
    0.0013f,0.0012f,0.0012f,0.0011f,0.0011f,0.0011f,0.0010f,0.0010f,0.0010f,0.0009f
};

// Scaled-domain activations: x is the pre-scaled exp2 argument.
__device__ __forceinline__ float sig2(float x) {
    return __builtin_amdgcn_rcpf(1.0f + __builtin_amdgcn_exp2f(x));
}
__device__ __forceinline__ float tanh2(float x) {
    return fmaf(2.0f, __builtin_amdgcn_rcpf(1.0f + __builtin_amdgcn_exp2f(x)), -1.0f);
}
__device__ __forceinline__ unsigned short tb(float x) {
    return (unsigned short)(__float_as_uint(x) >> 16);
}
__device__ __forceinline__ float fb(unsigned short h) {
    return __uint_as_float(((unsigned)h) << 16);
}

// A[128 rows][32 k], row r = u*4+q, PRE-SCALED by sc(q) = -log2e (i,f,o) / -2log2e (g):
//   u<30,  k<30 : sc*W_hh1[(q*30+u)*30+k]
//   u<30,  k==30: sc*W_ih1[(q*30+u)*13+12]   (avg column; B k=30 slot = AVG[t])
//   u==30, k<30 : sc*W_ih2[q*30+k]           (LSTM2 input dot rides the same MFMA)
// ws layout (float*): ushort whi[4096] @0; ushort wlo @2048; float bconst[128] @4096
//                     float wih1f[128*12] @4224; u32 avgpk[121] @5760 (hi|lo<<16)
__global__ void pack_weights(const float* __restrict__ w_ih1,
                             const float* __restrict__ w_hh1,
                             const float* __restrict__ b1,
                             const float* __restrict__ w_ih2,
                             const float* __restrict__ b2,
                             float* __restrict__ ws) {
    unsigned short* whi = (unsigned short*)ws;
    unsigned short* wlo = (unsigned short*)(ws + 2048);
    float* bconst = ws + 4096;
    float* wih1f  = ws + 4224;
    unsigned* avgpk = (unsigned*)(ws + 5760);
    const int tid = threadIdx.x;
    for (int idx = tid; idx < 4096; idx += 256) {
        const int T = idx >> 9, lane = (idx >> 3) & 63, j = idx & 7;
        const int r = 16 * T + (lane & 15);
        const int k = ((lane >> 4) & 3) * 8 + j;
        const int u = r >> 2, q = r & 3;
        const float sc = (q == 2) ? (-2.0f * LOG2E) : (-LOG2E);
        float v = 0.0f;
        if (u < 30) {
            if (k < 30)       v = w_hh1[(q * 30 + u) * 30 + k];
            else if (k == 30) v = w_ih1[(q * 30 + u) * 13 + 12];
        } else if (u == 30 && k < 30) {
            v = w_ih2[q * 30 + k];
        }
        v *= sc;
        const unsigned short hi = tb(v);
        whi[idx] = hi;
        wlo[idx] = tb(v - fb(hi));
    }
    for (int r = tid; r < 128; r += 256) {
        const int u = r >> 2, q = r & 3;
        const float sc = (q == 2) ? (-2.0f * LOG2E) : (-LOG2E);
        bconst[r] = sc * ((u < 30) ? b1[q * 30 + u] : ((u == 30) ? b2[q] : 0.0f));
    }
    for (int idx = tid; idx < 1536; idx += 256) {
        const int r = idx / 12, d = idx % 12;
        const int u = r >> 2, q = r & 3;
        const float sc = (q == 2) ? (-2.0f * LOG2E) : (-LOG2E);
        wih1f[idx] = (u < 30) ? sc * w_ih1[(q * 30 + u) * 13 + d] : 0.0f;
    }
    for (int t = tid; t < 121; t += 256) {
        const float a = (t < 120) ? AVG_D[t] : 0.0f;
        const unsigned short hi = tb(a);
        const unsigned short lo = tb(a - fb(hi));
        avgpk[t] = (unsigned)hi | ((unsigned)lo << 16);
    }
}

// Block = 128 threads = 2 waves; each wave owns A-row half [64wr,64wr+64) for
// TWO independent groups of 16 sequences (32 seqs/block). The two groups'
// dependency chains interleave within each wave (ILP covers MFMA/exp2 latency).
// h packed bf16 hi|lo in LDS; one barrier per step. Grid 1024 blocks (4/CU).
__global__ __launch_bounds__(128, 2)
void lstm_mfma_kernel(const float* __restrict__ feat,
                      const float* __restrict__ w_hh2,
                      const float* __restrict__ ws,
                      float* __restrict__ out) {
    __shared__ unsigned hx[2][2][32 * 17];            // [buf][grp] packed h, 8.7 KB
    __shared__ __align__(16) float out_s[32 * 124];   // h2 staging, 15.9 KB

    const int tid  = threadIdx.x;
    const int lane = tid & 63;
    const int wr   = __builtin_amdgcn_readfirstlane(tid >> 6);
    const int s    = lane & 15;
    const int quad = lane >> 4;
    const unsigned* avgpk = (const unsigned*)(ws + 5760);

    for (int i = tid; i < 2176; i += 128) (&hx[0][0][0])[i] = 0u;
    __syncthreads();
    if (tid < 32) hx[0][tid >> 4][30 * 17 + (tid & 15)] = avgpk[0];

    // ---- A fragments (pre-scaled weights), shared by both groups ----
    bf16x8 Ahi[4], Alo[4];
    {
        const unsigned short* whi = (const unsigned short*)ws;
        const unsigned short* wlo = (const unsigned short*)(ws + 2048);
#pragma unroll
        for (int Tl = 0; Tl < 4; Tl++) {
            Ahi[Tl] = *(const bf16x8*)(whi + (4 * wr + Tl) * 512 + lane * 8);
            Alo[Tl] = *(const bf16x8*)(wlo + (4 * wr + Tl) * 512 + lane * 8);
        }
    }

    // ---- per-sequence constant projections, both groups ----
    f32x4 projb[2][4];
    {
        const float* bconst = ws + 4096;
        const float* wih1f  = ws + 4224;
#pragma unroll
        for (int g = 0; g < 2; g++) {
            const int seq = blockIdx.x * 32 + g * 16 + s;
            const float4* fp = reinterpret_cast<const float4*>(feat + seq * 12);
            float4 A = fp[0], B = fp[1], C = fp[2];
            float f0[12] = { A.x,A.y,A.z,A.w, B.x,B.y,B.z,B.w, C.x,C.y,C.z,C.w };
#pragma unroll
            for (int Tl = 0; Tl < 4; Tl++) {
#pragma unroll
                for (int gg = 0; gg < 4; gg++) {
                    const int r = 64 * wr + 16 * Tl + 4 * quad + gg;
                    float acc = bconst[r];
#pragma unroll
                    for (int d = 0; d < 12; d++) acc = fmaf(f0[d], wih1f[r * 12 + d], acc);
                    projb[g][Tl][gg] = acc;
                }
            }
        }
    }

    float c1[2][4];
#pragma unroll
    for (int g = 0; g < 2; g++)
#pragma unroll
        for (int Tl = 0; Tl < 4; Tl++) c1[g][Tl] = 0.0f;
    float h2[2] = {0.0f, 0.0f}, c2[2] = {0.0f, 0.0f};
    const float whs0 = -LOG2E * w_hh2[0];
    const float whs1 = -LOG2E * w_hh2[1];
    const float whs2 = -2.0f * LOG2E * w_hh2[2];
    const float whs3 = -LOG2E * w_hh2[3];

    __syncthreads();

#pragma unroll 1
    for (int t = 0; t <= 120; t++) {
        const int buf = t & 1;

        // ---- B fragments for both groups: 16 packed reads + 16 perms ----
        bf16x8 Bhi[2], Blo[2];
#pragma unroll
        for (int g = 0; g < 2; g++) {
            const unsigned* hb = hx[buf][g];
            unsigned r0[8];
#pragma unroll
            for (int j = 0; j < 8; j++) r0[j] = hb[(8 * quad + j) * 17 + s];
            union { int4 i; bf16x8 v; } ubh, ubl;
            ubh.i.x = (int)__builtin_amdgcn_perm(r0[1], r0[0], 0x05040100u);
            ubh.i.y = (int)__builtin_amdgcn_perm(r0[3], r0[2], 0x05040100u);
            ubh.i.z = (int)__builtin_amdgcn_perm(r0[5], r0[4], 0x05040100u);
            ubh.i.w = (int)__builtin_amdgcn_perm(r0[7], r0[6], 0x05040100u);
            ubl.i.x = (int)__builtin_amdgcn_perm(r0[1], r0[0], 0x07060302u);
            ubl.i.y = (int)__builtin_amdgcn_perm(r0[3], r0[2], 0x07060302u);
            ubl.i.z = (int)__builtin_amdgcn_perm(r0[5], r0[4], 0x07060302u);
            ubl.i.w = (int)__builtin_amdgcn_perm(r0[7], r0[6], 0x07060302u);
            Bhi[g] = ubh.v; Blo[g] = ubl.v;
        }

        // ---- 24 MFMAs (two independent 12-chains interleaved) ----
        f32x4 D[2][4];
#pragma unroll
        for (int g = 0; g < 2; g++)
#pragma unroll
            for (int Tl = 0; Tl < 4; Tl++)
                D[g][Tl] = __builtin_amdgcn_mfma_f32_16x16x32_bf16(Alo[Tl], Bhi[g], projb[g][Tl], 0, 0, 0);
#pragma unroll
        for (int g = 0; g < 2; g++)
#pragma unroll
            for (int Tl = 0; Tl < 4; Tl++)
                D[g][Tl] = __builtin_amdgcn_mfma_f32_16x16x32_bf16(Ahi[Tl], Blo[g], D[g][Tl], 0, 0, 0);
#pragma unroll
        for (int g = 0; g < 2; g++)
#pragma unroll
            for (int Tl = 0; Tl < 4; Tl++)
                D[g][Tl] = __builtin_amdgcn_mfma_f32_16x16x32_bf16(Ahi[Tl], Bhi[g], D[g][Tl], 0, 0, 0);

        // ---- LSTM2 cells for step t-1 (wave1 tile3 rows 120..123, quad==2) ----
        if (t >= 1 && wr == 1 && quad == 2) {
#pragma unroll
            for (int g = 0; g < 2; g++) {
                const float g0 = fmaf(h2[g], whs0, D[g][3][0]);
                const float g1 = fmaf(h2[g], whs1, D[g][3][1]);
                const float g2 = fmaf(h2[g], whs2, D[g][3][2]);
                const float g3 = fmaf(h2[g], whs3, D[g][3][3]);
                c2[g] = sig2(g1) * c2[g] + sig2(g0) * tanh2(g2);
                h2[g] = sig2(g3) * tanh2(c2[g] * (-2.0f * LOG2E));
                out_s[(g * 16 + s) * 124 + (t - 1)] = h2[g];
            }
        }

        // ---- LSTM1 activations both groups; write packed bf16 h_t ----
        if (t < 120) {
#pragma unroll
            for (int g = 0; g < 2; g++) {
                unsigned* hn = hx[buf ^ 1][g];
#pragma unroll
                for (int Tl = 0; Tl < 4; Tl++) {
                    const int u = 16 * wr + 4 * Tl + quad;
                    if (u < 30) {
                        const float ck = sig2(D[g][Tl][1]) * c1[g][Tl]
                                       + sig2(D[g][Tl][0]) * tanh2(D[g][Tl][2]);
                        c1[g][Tl] = ck;
                        const float hk = sig2(D[g][Tl][3]) * tanh2(ck * (-2.0f * LOG2E));
                        const unsigned bits = __float_as_uint(hk);
                        const float rem = hk - __uint_as_float(bits & 0xffff0000u);
                        const unsigned lo = __float_as_uint(rem) >> 16;
                        hn[u * 17 + s] = (bits >> 16) | (lo << 16);
                    }
                }
            }
            if (wr == 1 && lane < 32)
                hx[buf ^ 1][lane >> 4][30 * 17 + (lane & 15)] = avgpk[t + 1];
        }

        __syncthreads();
    }

    // ---- coalesced flush: 32 seq x 120 t = 960 float4 by 128 threads ----
    float* outb = out + (size_t)blockIdx.x * 32 * 120;
#pragma unroll
    for (int it = 0; it < 8; it++) {
        const int fi = it * 128 + tid;
        if (fi < 960) {
            const int sq = fi / 30, j = fi % 30;
            const float4 v = *reinterpret_cast<const float4*>(&out_s[sq * 124 + j * 4]);
            *reinterpret_cast<float4*>(&outb[sq * 120 + j * 4]) = v;
        }
    }
}

extern "C" void kernel_launch(void* const* d_in, const int* in_sizes, int n_in,
                              void* d_out, int out_size, void* d_ws, size_t ws_size,
                              hipStream_t stream) {
    (void)in_sizes; (void)n_in; (void)out_size; (void)ws_size;
    const float* feat  = (const float*)d_in[0];
    const float* w_ih1 = (const float*)d_in[1];
    const float* w_hh1 = (const float*)d_in[2];
    const float* b1    = (const float*)d_in[3];
    const float* w_ih2 = (const float*)d_in[4];
    const float* w_hh2 = (const float*)d_in[5];
    const float* b2    = (const float*)d_in[6];
    float* ws  = (float*)d_ws;
    float* out = (float*)d_out;

    hipLaunchKernelGGL(pack_weights, dim3(1), dim3(256), 0, stream,
                       w_ih1, w_hh1, b1, w_ih2, b2, ws);
    hipLaunchKernelGGL(lstm_mfma_kernel, dim3(1024), dim3(128), 0, stream,
                       feat, w_hh2, ws, out);
}

// Round 10
// 257.530 us; speedup vs baseline: 1.1314x; 1.1314x over previous
//
#include <hip/hip_runtime.h>

typedef __attribute__((ext_vector_type(8))) short bf16x8;
typedef __attribute__((ext_vector_type(4))) float f32x4;

#define LOG2E 1.44269504088896340736f

// Average-trace constant from the Python module (length 120).
__device__ __constant__ float AVG_D[120] = {
    0.0256f,0.0823f,0.1157f,0.1315f,0.1366f,0.1369f,0.1347f,0.1308f,0.1259f,0.1205f,
    0.1146f,0.1086f,0.1028f,0.0970f,0.0913f,0.0858f,0.0805f,0.0756f,0.0708f,0.0664f,
    0.0623f,0.0584f,0.0549f,0.0515f,0.0485f,0.0456f,0.0429f,0.0404f,0.0381f,0.0360f,
    0.0340f,0.0321f,0.0304f,0.0287f,0.0272f,0.0258f,0.0245f,0.0233f,0.0222f,0.0211f,
    0.0201f,0.0191f,0.0182f,0.0173f,0.0165f,0.0158f,0.0150f,0.0143f,0.0137f,0.0130f,
    0.0125f,0.0119f,0.0114f,0.0108f,0.0104f,0.0099f,0.0095f,0.0091f,0.0087f,0.0083f,
    0.0080f,0.0077f,0.0074f,0.0071f,0.0068f,0.0065f,0.0062f,0.0060f,0.0058f,0.0055f,
    0.0053f,0.0050f,0.0049f,0.0047f,0.0045f,0.0044f,0.0042f,0.0040f,0.0039f,0.0038f,
    0.0036f,0.0034f,0.0033f,0.0032f,0.0031f,0.0030f,0.0029f,0.0028f,0.0027f,0.0026f,
    0.0025f,0.0024f,0.0023f,0.0022f,0.0021f,0.0021f,0.0020f,0.0019f,0.0018f,0.0018f,
    0.0017f,0.0017f,0.0016f,0.0016f,0.0015f,0.0015f,0.0014f,0.0014f,0.0013f,0.0013f,
    0.0013f,0.0012f,0.0012f,0.0011f,0.0011f,0.0011f,0.0010f,0.0010f,0.0010f,0.0009f
};

// Scaled-domain activations (x = pre-scaled exp2 argument); NaN-safe.
__device__ __forceinline__ float sig2(float x) {
    return __builtin_amdgcn_rcpf(1.0f + __builtin_amdgcn_exp2f(x));
}
__device__ __forceinline__ float tanh2(float x) {
    return fmaf(2.0f, __builtin_amdgcn_rcpf(1.0f + __builtin_amdgcn_exp2f(x)), -1.0f);
}
__device__ __forceinline__ unsigned short tb(float x) {
    return (unsigned short)(__float_as_uint(x) >> 16);
}
__device__ __forceinline__ float fb(unsigned short h) {
    return __uint_as_float(((unsigned)h) << 16);
}

// A[128 rows][32 k], row r = u*4+q, PRE-SCALED by sc(q) = -log2e (i,f,o) / -2log2e (g):
//   u<30,  k<30 : sc*W_hh1[(q*30+u)*30+k]
//   u<30,  k==30: sc*W_ih1[(q*30+u)*13+12]   (avg column; B k=30 slot = AVG[t])
//   u==30, k<30 : sc*W_ih2[q*30+k]           (LSTM2 input dot rides the same MFMA)
// ws layout (float*): ushort whi[4096] @0; ushort wlo @2048; float bconst[128] @4096
//                     float wih1f[128*12] @4224; u32 avgpk[121] @5760 (hi|lo<<16)
__global__ void pack_weights(const float* __restrict__ w_ih1,
                             const float* __restrict__ w_hh1,
                             const float* __restrict__ b1,
                             const float* __restrict__ w_ih2,
                             const float* __restrict__ b2,
                             float* __restrict__ ws) {
    unsigned short* whi = (unsigned short*)ws;
    unsigned short* wlo = (unsigned short*)(ws + 2048);
    float* bconst = ws + 4096;
    float* wih1f  = ws + 4224;
    unsigned* avgpk = (unsigned*)(ws + 5760);
    const int tid = threadIdx.x;
    for (int idx = tid; idx < 4096; idx += 256) {
        const int T = idx >> 9, lane = (idx >> 3) & 63, j = idx & 7;
        const int r = 16 * T + (lane & 15);
        const int k = ((lane >> 4) & 3) * 8 + j;
        const int u = r >> 2, q = r & 3;
        const float sc = (q == 2) ? (-2.0f * LOG2E) : (-LOG2E);
        float v = 0.0f;
        if (u < 30) {
            if (k < 30)       v = w_hh1[(q * 30 + u) * 30 + k];
            else if (k == 30) v = w_ih1[(q * 30 + u) * 13 + 12];
        } else if (u == 30 && k < 30) {
            v = w_ih2[q * 30 + k];
        }
        v *= sc;
        const unsigned short hi = tb(v);
        whi[idx] = hi;
        wlo[idx] = tb(v - fb(hi));
    }
    for (int r = tid; r < 128; r += 256) {
        const int u = r >> 2, q = r & 3;
        const float sc = (q == 2) ? (-2.0f * LOG2E) : (-LOG2E);
        bconst[r] = sc * ((u < 30) ? b1[q * 30 + u] : ((u == 30) ? b2[q] : 0.0f));
    }
    for (int idx = tid; idx < 1536; idx += 256) {
        const int r = idx / 12, d = idx % 12;
        const int u = r >> 2, q = r & 3;
        const float sc = (q == 2) ? (-2.0f * LOG2E) : (-LOG2E);
        wih1f[idx] = (u < 30) ? sc * w_ih1[(q * 30 + u) * 13 + d] : 0.0f;
    }
    for (int t = tid; t < 121; t += 256) {
        const float a = (t < 120) ? AVG_D[t] : 0.0f;
        const unsigned short hi = tb(a);
        const unsigned short lo = tb(a - fb(hi));
        avgpk[t] = (unsigned)hi | ((unsigned)lo << 16);
    }
}

// Block = 128 threads = 2 waves over the SAME 16 sequences; wave wr owns A-rows
// [64wr,64wr+64). h in LDS packed bf16 hi|lo, SEQ-MAJOR stride 36: B-build is
// 2 aligned ds_read_b128 + 8 v_perm; activation writes are conflict-free.
// LSTM1 cell algebraically rcp-fused: 7 trans/unit-group instead of 10.
// One barrier per step. Grid 2048 blocks = 4096 waves.
__global__ __launch_bounds__(128, 4)
void lstm_mfma_kernel(const float* __restrict__ feat,
                      const float* __restrict__ w_hh2,
                      const float* __restrict__ ws,
                      float* __restrict__ out) {
    __shared__ __align__(16) unsigned hx[2][16 * 36]; // [buf][seq*36+u] packed h, 4.6 KB
    __shared__ __align__(16) float out_s[16 * 124];   // h2 staging, 7.9 KB

    const int tid  = threadIdx.x;
    const int lane = tid & 63;
    const int wr   = __builtin_amdgcn_readfirstlane(tid >> 6);
    const int s    = lane & 15;
    const int quad = lane >> 4;
    const int seq  = blockIdx.x * 16 + s;
    const unsigned* avgpk = (const unsigned*)(ws + 5760);

    // zero both buffers (u=31 pad must stay 0); seed AVG[0] in buf0 u=30 slots
    for (int i = tid; i < 1152; i += 128) (&hx[0][0])[i] = 0u;
    __syncthreads();
    if (tid < 16) hx[0][tid * 36 + 30] = avgpk[0];

    // ---- A fragments (pre-scaled weights), 4 tiles ----
    bf16x8 Ahi[4], Alo[4];
    {
        const unsigned short* whi = (const unsigned short*)ws;
        const unsigned short* wlo = (const unsigned short*)(ws + 2048);
#pragma unroll
        for (int Tl = 0; Tl < 4; Tl++) {
            Ahi[Tl] = *(const bf16x8*)(whi + (4 * wr + Tl) * 512 + lane * 8);
            Alo[Tl] = *(const bf16x8*)(wlo + (4 * wr + Tl) * 512 + lane * 8);
        }
    }

    // ---- per-sequence constant projection (scaled domain) ----
    float f0[12];
    {
        const float4* fp = reinterpret_cast<const float4*>(feat + seq * 12);
        float4 A = fp[0], B = fp[1], C = fp[2];
        f0[0]=A.x; f0[1]=A.y; f0[2]=A.z; f0[3]=A.w;
        f0[4]=B.x; f0[5]=B.y; f0[6]=B.z; f0[7]=B.w;
        f0[8]=C.x; f0[9]=C.y; f0[10]=C.z; f0[11]=C.w;
    }
    f32x4 projb[4];
    {
        const float* bconst = ws + 4096;
        const float* wih1f  = ws + 4224;
#pragma unroll
        for (int Tl = 0; Tl < 4; Tl++) {
#pragma unroll
            for (int g = 0; g < 4; g++) {
                const int r = 64 * wr + 16 * Tl + 4 * quad + g;
                float acc = bconst[r];
#pragma unroll
                for (int d = 0; d < 12; d++) acc = fmaf(f0[d], wih1f[r * 12 + d], acc);
                projb[Tl][g] = acc;
            }
        }
    }

    float c1[4];
#pragma unroll
    for (int Tl = 0; Tl < 4; Tl++) c1[Tl] = 0.0f;
    float h2 = 0.0f, c2 = 0.0f;
    const float whs0 = -LOG2E * w_hh2[0];
    const float whs1 = -LOG2E * w_hh2[1];
    const float whs2 = -2.0f * LOG2E * w_hh2[2];
    const float whs3 = -LOG2E * w_hh2[3];

    __syncthreads();

#pragma unroll 1
    for (int t = 0; t <= 120; t++) {
        const int buf = t & 1;
        const unsigned* hb = hx[buf];
        unsigned*       hn = hx[buf ^ 1];

        // ---- B fragment: 2 ds_read_b128 (units 8q..8q+7 of seq s) + 8 perms ----
        const uint4 Ra = *reinterpret_cast<const uint4*>(hb + s * 36 + 8 * quad);
        const uint4 Rb = *reinterpret_cast<const uint4*>(hb + s * 36 + 8 * quad + 4);
        union { int4 i; bf16x8 v; } ubh, ubl;
        ubh.i.x = (int)__builtin_amdgcn_perm(Ra.y, Ra.x, 0x05040100u);
        ubh.i.y = (int)__builtin_amdgcn_perm(Ra.w, Ra.z, 0x05040100u);
        ubh.i.z = (int)__builtin_amdgcn_perm(Rb.y, Rb.x, 0x05040100u);
        ubh.i.w = (int)__builtin_amdgcn_perm(Rb.w, Rb.z, 0x05040100u);
        ubl.i.x = (int)__builtin_amdgcn_perm(Ra.y, Ra.x, 0x07060302u);
        ubl.i.y = (int)__builtin_amdgcn_perm(Ra.w, Ra.z, 0x07060302u);
        ubl.i.z = (int)__builtin_amdgcn_perm(Rb.y, Rb.x, 0x07060302u);
        ubl.i.w = (int)__builtin_amdgcn_perm(Rb.w, Rb.z, 0x07060302u);
        const bf16x8 Bhi = ubh.v, Blo = ubl.v;

        // ---- 12 MFMAs: D = Ahi*Bhi + Ahi*Blo + Alo*Bhi + projb ----
        f32x4 D[4];
#pragma unroll
        for (int Tl = 0; Tl < 4; Tl++)
            D[Tl] = __builtin_amdgcn_mfma_f32_16x16x32_bf16(Alo[Tl], Bhi, projb[Tl], 0, 0, 0);
#pragma unroll
        for (int Tl = 0; Tl < 4; Tl++)
            D[Tl] = __builtin_amdgcn_mfma_f32_16x16x32_bf16(Ahi[Tl], Blo, D[Tl], 0, 0, 0);
#pragma unroll
        for (int Tl = 0; Tl < 4; Tl++)
            D[Tl] = __builtin_amdgcn_mfma_f32_16x16x32_bf16(Ahi[Tl], Bhi, D[Tl], 0, 0, 0);

        // ---- LSTM2 cell for step t-1 (wave1 tile3 rows 120..123, quad==2) ----
        // Unfused (safe form): exp2 args here can reach ~92, fusion would overflow.
        if (t >= 1 && wr == 1 && quad == 2) {
            const float g0 = fmaf(h2, whs0, D[3][0]);
            const float g1 = fmaf(h2, whs1, D[3][1]);
            const float g2 = fmaf(h2, whs2, D[3][2]);
            const float g3 = fmaf(h2, whs3, D[3][3]);
            c2 = sig2(g1) * c2 + sig2(g0) * tanh2(g2);
            h2 = sig2(g3) * tanh2(c2 * (-2.0f * LOG2E));
            out_s[s * 124 + (t - 1)] = h2;
        }

        // ---- LSTM1 fused activations (7 trans/group); write packed bf16 h_t ----
        if (t < 120) {
#pragma unroll
            for (int Tl = 0; Tl < 4; Tl++) {
                const int u = 16 * wr + 4 * Tl + quad;
                if (u < 30) {
                    const float ei = __builtin_amdgcn_exp2f(D[Tl][0]);
                    const float ef = __builtin_amdgcn_exp2f(D[Tl][1]);
                    const float eg = __builtin_amdgcn_exp2f(D[Tl][2]);
                    const float eo = __builtin_amdgcn_exp2f(D[Tl][3]);
                    const float pi_ = 1.0f + ei, pf = 1.0f + ef;
                    const float pg  = 1.0f + eg, po = 1.0f + eo;
                    const float pig = pi_ * pg;
                    // ck = c/pf + (1-eg)/(pi*pg)  -> single rcp
                    const float num = fmaf(c1[Tl], pig, (1.0f - eg) * pf);
                    const float ck  = num * __builtin_amdgcn_rcpf(pf * pig);
                    c1[Tl] = ck;
                    // h = sig(o)*tanh(ck) = (1-ec)/(po*(1+ec)) -> single rcp
                    float carg = -2.0f * LOG2E * ck;
                    carg = fminf(fmaxf(carg, -80.0f), 80.0f);   // v_med3 clamp
                    const float ec = __builtin_amdgcn_exp2f(carg);
                    const float hk = (1.0f - ec) *
                                     __builtin_amdgcn_rcpf(po * (1.0f + ec));
                    const unsigned hbits = __float_as_uint(hk);
                    const float rem = hk - __uint_as_float(hbits & 0xffff0000u);
                    hn[s * 36 + u] = __builtin_amdgcn_perm(
                        __float_as_uint(rem), hbits, 0x07060302u);
                }
            }
            if (wr == 1 && lane < 16) hn[lane * 36 + 30] = avgpk[t + 1];
        }

        __syncthreads();
    }

    // ---- coalesced flush: 16 seq x 120 t = 480 float4 by 128 threads ----
    float* outb = out + (size_t)blockIdx.x * 16 * 120;
#pragma unroll
    for (int it = 0; it < 4; it++) {
        const int fi = it * 128 + tid;
        if (fi < 480) {
            const int sq = fi / 30, j = fi % 30;
            const float4 v = *reinterpret_cast<const float4*>(&out_s[sq * 124 + j * 4]);
            *reinterpret_cast<float4*>(&outb[sq * 120 + j * 4]) = v;
        }
    }
}

extern "C" void kernel_launch(void* const* d_in, const int* in_sizes, int n_in,
                              void* d_out, int out_size, void* d_ws, size_t ws_size,
                              hipStream_t stream) {
    (void)in_sizes; (void)n_in; (void)out_size; (void)ws_size;
    const float* feat  = (const float*)d_in[0];
    const float* w_ih1 = (const float*)d_in[1];
    const float* w_hh1 = (const float*)d_in[2];
    const float* b1    = (const float*)d_in[3];
    const float* w_ih2 = (const float*)d_in[4];
    const float* w_hh2 = (const float*)d_in[5];
    const float* b2    = (const float*)d_in[6];
    float* ws  = (float*)d_ws;
    float* out = (float*)d_out;

    hipLaunchKernelGGL(pack_weights, dim3(1), dim3(256), 0, stream,
                       w_ih1, w_hh1, b1, w_ih2, b2, ws);
    hipLaunchKernelGGL(lstm_mfma_kernel, dim3(2048), dim3(128), 0, stream,
                       feat, w_hh2, ws, out);
}

// Round 12
// 244.994 us; speedup vs baseline: 1.1893x; 1.0512x over previous
//
#include <hip/hip_runtime.h>

typedef __attribute__((ext_vector_type(8))) short bf16x8;
typedef __attribute__((ext_vector_type(4))) float f32x4;

#define LOG2E 1.44269504088896340736f

// Average-trace constant from the Python module (length 120).
__device__ __constant__ float AVG_D[120] = {
    0.0256f,0.0823f,0.1157f,0.1315f,0.1366f,0.1369f,0.1347f,0.1308f,0.1259f,0.1205f,
    0.1146f,0.1086f,0.1028f,0.0970f,0.0913f,0.0858f,0.0805f,0.0756f,0.0708f,0.0664f,
    0.0623f,0.0584f,0.0549f,0.0515f,0.0485f,0.0456f,0.0429f,0.0404f,0.0381f,0.0360f,
    0.0340f,0.0321f,0.0304f,0.0287f,0.0272f,0.0258f,0.0245f,0.0233f,0.0222f,0.0211f,
    0.0201f,0.0191f,0.0182f,0.0173f,0.0165f,0.0158f,0.0150f,0.0143f,0.0137f,0.0130f,
    0.0125f,0.0119f,0.0114f,0.0108f,0.0104f,0.0099f,0.0095f,0.0091f,0.0087f,0.0083f,
    0.0080f,0.0077f,0.0074f,0.0071f,0.0068f,0.0065f,0.0062f,0.0060f,0.0058f,0.0055f,
    0.0053f,0.0050f,0.0049f,0.0047f,0.0045f,0.0044f,0.0042f,0.0040f,0.0039f,0.0038f,
    0.0036f,0.0034f,0.0033f,0.0032f,0.0031f,0.0030f,0.0029f,0.0028f,0.0027f,0.0026f,
    0.0025f,0.0024f,0.0023f,0.0022f,0.0021f,0.0021f,0.0020f,0.0019f,0.0018f,0.0018f,
    0.0017f,0.0017f,0.0016f,0.0016f,0.0015f,0.0015f,0.0014f,0.0014f,0.0013f,0.0013f,
    0.0013f,0.0012f,0.0012f,0.0011f,0.0011f,0.0011f,0.0010f,0.0010f,0.0010f,0.0009f
};

__device__ __forceinline__ float sig2(float x) {
    return __builtin_amdgcn_rcpf(1.0f + __builtin_amdgcn_exp2f(x));
}
__device__ __forceinline__ float tanh2(float x) {
    return fmaf(2.0f, __builtin_amdgcn_rcpf(1.0f + __builtin_amdgcn_exp2f(x)), -1.0f);
}
__device__ __forceinline__ unsigned short tb(float x) {          // truncate fp32 -> bf16
    return (unsigned short)(__float_as_uint(x) >> 16);
}
__device__ __forceinline__ float fb(unsigned short h) {
    return __uint_as_float(((unsigned)h) << 16);
}

// A[128 rows][32 k], row r = u*4+q, PRE-SCALED by sc(q) = -log2e (i,f,o) / -2log2e (g):
//   u<30,  k<30 : sc*W_hh1[(q*30+u)*30+k]
//   u<30,  k==30: sc*W_ih1[(q*30+u)*13+12]   (avg column; B k=30 slot = AVG[t])
//   u==30, k<30 : sc*W_ih2[q*30+k]           (LSTM2 input dot rides the same MFMA)
// ws layout (float*): ushort whi[4096] @0; ushort wlo @2048; float bconst[128] @4096
//                     float wih1f[128*12] @4224; u32 avgpk[121] @5760 (hi|lo<<16)
__global__ void pack_weights(const float* __restrict__ w_ih1,
                             const float* __restrict__ w_hh1,
                             const float* __restrict__ b1,
                             const float* __restrict__ w_ih2,
                             const float* __restrict__ b2,
                             float* __restrict__ ws) {
    unsigned short* whi = (unsigned short*)ws;
    unsigned short* wlo = (unsigned short*)(ws + 2048);
    float* bconst = ws + 4096;
    float* wih1f  = ws + 4224;
    unsigned* avgpk = (unsigned*)(ws + 5760);
    const int tid = threadIdx.x;
    for (int idx = tid; idx < 4096; idx += 256) {
        const int T = idx >> 9, lane = (idx >> 3) & 63, j = idx & 7;
        const int r = 16 * T + (lane & 15);
        const int k = ((lane >> 4) & 3) * 8 + j;
        const int u = r >> 2, q = r & 3;
        const float sc = (q == 2) ? (-2.0f * LOG2E) : (-LOG2E);
        float v = 0.0f;
        if (u < 30) {
            if (k < 30)       v = w_hh1[(q * 30 + u) * 30 + k];
            else if (k == 30) v = w_ih1[(q * 30 + u) * 13 + 12];
        } else if (u == 30 && k < 30) {
            v = w_ih2[q * 30 + k];
        }
        v *= sc;
        const unsigned short hi = tb(v);
        whi[idx] = hi;
        wlo[idx] = tb(v - fb(hi));
    }
    for (int r = tid; r < 128; r += 256) {
        const int u = r >> 2, q = r & 3;
        const float sc = (q == 2) ? (-2.0f * LOG2E) : (-LOG2E);
        bconst[r] = sc * ((u < 30) ? b1[q * 30 + u] : ((u == 30) ? b2[q] : 0.0f));
    }
    for (int idx = tid; idx < 1536; idx += 256) {
        const int r = idx / 12, d = idx % 12;
        const int u = r >> 2, q = r & 3;
        const float sc = (q == 2) ? (-2.0f * LOG2E) : (-LOG2E);
        wih1f[idx] = (u < 30) ? sc * w_ih1[(q * 30 + u) * 13 + d] : 0.0f;
    }
    for (int t = tid; t < 121; t += 256) {
        const float a = (t < 120) ? AVG_D[t] : 0.0f;
        const unsigned short hi = tb(a);
        const unsigned short lo = tb(a - fb(hi));
        avgpk[t] = (unsigned)hi | ((unsigned)lo << 16);
    }
}

// Block = 128 threads = 2 INDEPENDENT waves; each wave owns ALL 128 A-rows
// (8 tiles) for its own 16 sequences. h lives in a per-wave LDS buffer
// (packed bf16 hi|lo u32, seq-major stride 36): intra-wave DS-pipe ordering
// makes the recurrence correct with NO __syncthreads in the hot loop
// (R6-verified). Fused activations (7 trans/unit), 2xds_read_b128 B-build.
// Grid 1024 blocks = 2048 waves = 2 waves/SIMD (structural: 32768 seqs / 16).
__global__ __launch_bounds__(128, 2)
void lstm_mfma_kernel(const float* __restrict__ feat,
                      const float* __restrict__ w_hh2,
                      const float* __restrict__ ws,
                      float* __restrict__ out) {
    __shared__ __align__(16) unsigned hx[2][2][16 * 36]; // [wave][buf] 9.2 KB
    __shared__ __align__(16) float out_s[32 * 124];      // h2 staging, 15.9 KB

    const int tid  = threadIdx.x;
    const int lane = tid & 63;
    const int wv   = __builtin_amdgcn_readfirstlane(tid >> 6);
    const int s    = lane & 15;
    const int quad = lane >> 4;
    const int seq  = blockIdx.x * 32 + wv * 16 + s;
    const unsigned* avgpk = (const unsigned*)(ws + 5760);

    // zero both waves' buffers (pads must stay 0); seed AVG[0] in each buf0
    for (int i = tid; i < 2304; i += 128) (&hx[0][0][0])[i] = 0u;
    __syncthreads();
    if (tid < 32) hx[tid >> 4][0][(tid & 15) * 36 + 30] = avgpk[0];

    // ---- A fragments (pre-scaled, exact hi/lo split), all 8 tiles ----
    bf16x8 Ahi[8], Alo[8];
    {
        const unsigned short* whi = (const unsigned short*)ws;
        const unsigned short* wlo = (const unsigned short*)(ws + 2048);
#pragma unroll
        for (int T = 0; T < 8; T++) {
            Ahi[T] = *(const bf16x8*)(whi + T * 512 + lane * 8);
            Alo[T] = *(const bf16x8*)(wlo + T * 512 + lane * 8);
        }
    }

    // ---- per-sequence constant projection (scaled domain), 8 tiles ----
    float f0[12];
    {
        const float4* fp = reinterpret_cast<const float4*>(feat + seq * 12);
        float4 A = fp[0], B = fp[1], C = fp[2];
        f0[0]=A.x; f0[1]=A.y; f0[2]=A.z; f0[3]=A.w;
        f0[4]=B.x; f0[5]=B.y; f0[6]=B.z; f0[7]=B.w;
        f0[8]=C.x; f0[9]=C.y; f0[10]=C.z; f0[11]=C.w;
    }
    f32x4 projb[8];
    {
        const float* bconst = ws + 4096;
        const float* wih1f  = ws + 4224;
#pragma unroll
        for (int T = 0; T < 8; T++) {
#pragma unroll
            for (int g = 0; g < 4; g++) {
                const int r = 16 * T + 4 * quad + g;
                float acc = bconst[r];
#pragma unroll
                for (int d = 0; d < 12; d++) acc = fmaf(f0[d], wih1f[r * 12 + d], acc);
                projb[T][g] = acc;
            }
        }
    }

    float c1[8];
#pragma unroll
    for (int T = 0; T < 8; T++) c1[T] = 0.0f;
    float h2 = 0.0f, c2 = 0.0f;
    const float whs0 = -LOG2E * w_hh2[0];
    const float whs1 = -LOG2E * w_hh2[1];
    const float whs2 = -2.0f * LOG2E * w_hh2[2];
    const float whs3 = -LOG2E * w_hh2[3];

    __syncthreads();   // avg seed (written cross-wave) visible; last barrier before flush

#pragma unroll 1
    for (int t = 0; t <= 120; t++) {
        const int buf = t & 1;
        const unsigned* hb = hx[wv][buf];
        unsigned*       hn = hx[wv][buf ^ 1];

        // ---- B fragment: 2 ds_read_b128 + 8 perms (units 8q..8q+7, seq s) ----
        const uint4 Ra = *reinterpret_cast<const uint4*>(hb + s * 36 + 8 * quad);
        const uint4 Rb = *reinterpret_cast<const uint4*>(hb + s * 36 + 8 * quad + 4);
        union { int4 i; bf16x8 v; } ubh, ubl;
        ubh.i.x = (int)__builtin_amdgcn_perm(Ra.y, Ra.x, 0x05040100u);
        ubh.i.y = (int)__builtin_amdgcn_perm(Ra.w, Ra.z, 0x05040100u);
        ubh.i.z = (int)__builtin_amdgcn_perm(Rb.y, Rb.x, 0x05040100u);
        ubh.i.w = (int)__builtin_amdgcn_perm(Rb.w, Rb.z, 0x05040100u);
        ubl.i.x = (int)__builtin_amdgcn_perm(Ra.y, Ra.x, 0x07060302u);
        ubl.i.y = (int)__builtin_amdgcn_perm(Ra.w, Ra.z, 0x07060302u);
        ubl.i.z = (int)__builtin_amdgcn_perm(Rb.y, Rb.x, 0x07060302u);
        ubl.i.w = (int)__builtin_amdgcn_perm(Rb.w, Rb.z, 0x07060302u);
        const bf16x8 Bhi = ubh.v, Blo = ubl.v;

        // ---- 24 MFMAs: D = Ahi*Bhi + Ahi*Blo + Alo*Bhi + projb ----
        f32x4 D[8];
#pragma unroll
        for (int T = 0; T < 8; T++)
            D[T] = __builtin_amdgcn_mfma_f32_16x16x32_bf16(Alo[T], Bhi, projb[T], 0, 0, 0);
#pragma unroll
        for (int T = 0; T < 8; T++)
            D[T] = __builtin_amdgcn_mfma_f32_16x16x32_bf16(Ahi[T], Blo, D[T], 0, 0, 0);
#pragma unroll
        for (int T = 0; T < 8; T++)
            D[T] = __builtin_amdgcn_mfma_f32_16x16x32_bf16(Ahi[T], Bhi, D[T], 0, 0, 0);

        // ---- LSTM2 cell for step t-1 (tile7 rows 120..123, quad==2 lanes) ----
        if (t >= 1 && quad == 2) {
            const float g0 = fmaf(h2, whs0, D[7][0]);
            const float g1 = fmaf(h2, whs1, D[7][1]);
            const float g2 = fmaf(h2, whs2, D[7][2]);
            const float g3 = fmaf(h2, whs3, D[7][3]);
            c2 = sig2(g1) * c2 + sig2(g0) * tanh2(g2);
            h2 = sig2(g3) * tanh2(c2 * (-2.0f * LOG2E));
            out_s[(wv * 16 + s) * 124 + (t - 1)] = h2;
        }

        // ---- LSTM1 fused activations (u=4T+quad); write packed bf16 h_t ----
        if (t < 120) {
#pragma unroll
            for (int T = 0; T < 8; T++) {
                const int u = 4 * T + quad;
                if (u < 30) {
                    const float ei = __builtin_amdgcn_exp2f(D[T][0]);
                    const float ef = __builtin_amdgcn_exp2f(D[T][1]);
                    const float eg = __builtin_amdgcn_exp2f(D[T][2]);
                    const float eo = __builtin_amdgcn_exp2f(D[T][3]);
                    const float pi_ = 1.0f + ei, pf = 1.0f + ef;
                    const float pg  = 1.0f + eg, po = 1.0f + eo;
                    const float pig = pi_ * pg;
                    const float num = fmaf(c1[T], pig, (1.0f - eg) * pf);
                    const float ck  = num * __builtin_amdgcn_rcpf(pf * pig);
                    c1[T] = ck;
                    float carg = -2.0f * LOG2E * ck;
                    carg = fminf(fmaxf(carg, -80.0f), 80.0f);
                    const float ec = __builtin_amdgcn_exp2f(carg);
                    const float hk = (1.0f - ec) *
                                     __builtin_amdgcn_rcpf(po * (1.0f + ec));
                    const unsigned hbits = __float_as_uint(hk);
                    const float rem = hk - __uint_as_float(hbits & 0xffff0000u);
                    hn[s * 36 + u] = __builtin_amdgcn_perm(
                        __float_as_uint(rem), hbits, 0x07060302u);
                }
            }
            if (lane < 16) hn[lane * 36 + 30] = avgpk[t + 1];
        }
        // no barrier: hb/hn are private to this wave; DS pipe is in-order per wave
    }

    __syncthreads();
    // ---- coalesced flush: 32 seq x 120 t = 960 float4 by 128 threads ----
    float* outb = out + (size_t)blockIdx.x * 32 * 120;
#pragma unroll
    for (int it = 0; it < 8; it++) {
        const int fi = it * 128 + tid;
        if (fi < 960) {
            const int sq = fi / 30, j = fi % 30;
            const float4 v = *reinterpret_cast<const float4*>(&out_s[sq * 124 + j * 4]);
            *reinterpret_cast<float4*>(&outb[sq * 120 + j * 4]) = v;
        }
    }
}

extern "C" void kernel_launch(void* const* d_in, const int* in_sizes, int n_in,
                              void* d_out, int out_size, void* d_ws, size_t ws_size,
                              hipStream_t stream) {
    (void)in_sizes; (void)n_in; (void)out_size; (void)ws_size;
    const float* feat  = (const float*)d_in[0];
    const float* w_ih1 = (const float*)d_in[1];
    const float* w_hh1 = (const float*)d_in[2];
    const float* b1    = (const float*)d_in[3];
    const float* w_ih2 = (const float*)d_in[4];
    const float* w_hh2 = (const float*)d_in[5];
    const float* b2    = (const float*)d_in[6];
    float* ws  = (float*)d_ws;
    float* out = (float*)d_out;

    hipLaunchKernelGGL(pack_weights, dim3(1), dim3(256), 0, stream,
                       w_ih1, w_hh1, b1, w_ih2, b2, ws);
    hipLaunchKernelGGL(lstm_mfma_kernel, dim3(1024), dim3(128), 0, stream,
                       feat, w_hh2, ws, out);
}